// Round 5
// baseline (569.774 us; speedup 1.0000x reference)
//
#include <hip/hip_runtime.h>

#define NBINS 16
#define TPB   256
#define GRID  1280          // 5 blocks/CU x 256 CUs (32KB LDS -> exactly 5 co-resident)

// d_ws layout: partial[c * GRID + blk], c: 0..15 sum, 16..31 sumsq, 32..47 cnt,
// 48 = sum (wq-w)^2.  Then cells[49] staging at partial + 49*GRID.
// History: LDS atomics (CAS R1: 1026us, ds_add_f32 R3: 1010us) are ~6x slower
// than plain RMW (R2/R4: ~165us). Bank conflicts were NOT the limiter (R4).
// This round: counts via ballot (no DS), LDS=32KB exactly -> 20 waves/CU.

__global__ __launch_bounds__(TPB, 5) void binreg_main(
    const float* __restrict__ w, const float* __restrict__ wq,
    const float* __restrict__ alpha_p, const int* __restrict__ nbit_p,
    float* __restrict__ partial, long long n)
{
    // {sum, sumsq} per (bin, thread); column layout: addr = bin*256+tid ->
    // bank = tid%32 regardless of data-dependent bin (2-way aliasing = free).
    __shared__ float2 sv[NBINS * TPB];          // 32768 B exactly

    const int tid = threadIdx.x;

    #pragma unroll
    for (int k = 0; k < NBINS; ++k) sv[k * TPB + tid] = make_float2(0.0f, 0.0f);
    // columns are thread-private; no barrier needed until epilogue

    const float inv_a = 1.0f / alpha_p[0];
    const int   qoff  = 1 << (nbit_p[0] - 1);   // -Qn = 8 for nbit=4

    const long long n4     = n >> 2;
    const long long stride = (long long)GRID * TPB;
    const float4* w4 = (const float4*)w;
    const float4* q4 = (const float4*)wq;

    float sq = 0.0f;
    int cnt[NBINS];
    #pragma unroll
    for (int k = 0; k < NBINS; ++k) cnt[k] = 0;

    long long i = (long long)blockIdx.x * TPB + tid;
    bool valid = i < n4;
    float4 a, b;
    if (valid) { a = w4[i]; b = q4[i]; }

    while (valid) {
        // prefetch next iteration a full loop body ahead
        long long ni = i + stride;
        bool nvalid = ni < n4;
        float4 an, bn;
        if (nvalid) { an = w4[ni]; bn = q4[ni]; }

        float d0 = b.x - a.x, d1 = b.y - a.y, d2 = b.z - a.z, d3 = b.w - a.w;
        sq += d0 * d0 + d1 * d1 + d2 * d2 + d3 * d3;

        int b0 = ((int)rintf(b.x * inv_a) + qoff) & (NBINS - 1);
        int b1 = ((int)rintf(b.y * inv_a) + qoff) & (NBINS - 1);
        int b2 = ((int)rintf(b.z * inv_a) + qoff) & (NBINS - 1);
        int b3 = ((int)rintf(b.w * inv_a) + qoff) & (NBINS - 1);

        // counts: wave-uniform scalar accumulation, zero DS ops.
        // lane 0 always runs >= as many iters as any lane in its wave
        // (i ascends with lane), so lane 0's copy is canonical.
        #pragma unroll
        for (int k = 0; k < NBINS; ++k) {
            cnt[k] += __popcll(__ballot(b0 == k));
            cnt[k] += __popcll(__ballot(b1 == k));
            cnt[k] += __popcll(__ballot(b2 == k));
            cnt[k] += __popcll(__ballot(b3 == k));
        }

        int i0 = (b0 << 8) + tid;
        int i1 = (b1 << 8) + tid;
        int i2 = (b2 << 8) + tid;
        int i3 = (b3 << 8) + tid;

        // 4 RMW segments; may alias each other (same-bin components) so they
        // must stay in program order — in-order DS pipe makes that correct.
        { float2 t = sv[i0]; t.x += a.x; t.y += a.x * a.x; sv[i0] = t; }
        { float2 t = sv[i1]; t.x += a.y; t.y += a.y * a.y; sv[i1] = t; }
        { float2 t = sv[i2]; t.x += a.z; t.y += a.z * a.z; sv[i2] = t; }
        { float2 t = sv[i3]; t.x += a.w; t.y += a.w * a.w; sv[i3] = t; }

        i = ni; valid = nvalid; a = an; b = bn;
    }

    // scalar tail (n divisible by 4 in practice; safety only)
    for (long long t4 = (n4 << 2) + (long long)blockIdx.x * TPB + tid; t4 < n; t4 += stride) {
        float av = w[t4], bv = wq[t4];
        float d = bv - av;
        sq += d * d;
        int bb = ((int)rintf(bv * inv_a) + qoff) & (NBINS - 1);
        #pragma unroll
        for (int k = 0; k < NBINS; ++k) cnt[k] += __popcll(__ballot(bb == k));
        int ii = (bb << 8) + tid;
        float2 t = sv[ii]; t.x += av; t.y += av * av; sv[ii] = t;
    }

    // wave-reduce sq
    for (int off = 32; off; off >>= 1) sq += __shfl_down(sq, off, 64);
    const int wave = tid >> 6, lane = tid & 63;
    __syncthreads();   // all sv columns final & visible

    // fold 256 columns -> 32 block partials (s, ss); wave v: cells v, v+4, ...
    for (int c = wave; c < 32; c += 4) {
        const int bin = c & 15;
        float v = 0.0f;
        #pragma unroll
        for (int r = 0; r < TPB / 64; ++r) {
            float2 t = sv[(bin << 8) + r * 64 + lane];
            v += (c < 16) ? t.x : t.y;
        }
        for (int off = 32; off; off >>= 1) v += __shfl_down(v, off, 64);
        if (lane == 0) partial[c * GRID + blockIdx.x] = v;
    }
    __syncthreads();   // fold complete; sv reusable as staging

    float* stage = (float*)sv;   // 68 floats reused
    if (lane == 0) {
        #pragma unroll
        for (int k = 0; k < NBINS; ++k) stage[wave * NBINS + k] = (float)cnt[k];
        stage[64 + wave] = sq;
    }
    __syncthreads();

    if (tid < NBINS) {
        float v = stage[tid] + stage[16 + tid] + stage[32 + tid] + stage[48 + tid];
        partial[(32 + tid) * GRID + blockIdx.x] = v;
    }
    if (tid == 16)
        partial[48 * GRID + blockIdx.x] =
            (stage[64] + stage[65]) + (stage[66] + stage[67]);
}

// stage 1: one block per cell, reduce GRID partials -> cells[c]
__global__ __launch_bounds__(TPB) void binreg_final1(
    const float* __restrict__ partial, float* __restrict__ cells)
{
    const int c = blockIdx.x;
    const int tid = threadIdx.x, wave = tid >> 6, lane = tid & 63;
    __shared__ float wsum[4];

    float v = 0.0f;
    for (int r = tid; r < GRID; r += TPB) v += partial[c * GRID + r];
    for (int off = 32; off; off >>= 1) v += __shfl_down(v, off, 64);
    if (lane == 0) wsum[wave] = v;
    __syncthreads();
    if (tid == 0) cells[c] = (wsum[0] + wsum[1]) + (wsum[2] + wsum[3]);
}

// stage 2: combine 49 cells into the loss scalar
__global__ void binreg_final2(const float* __restrict__ cells,
                              float* __restrict__ out, long long n)
{
    if (threadIdx.x == 0 && blockIdx.x == 0) {
        float loss = cells[48] / (float)n;   // mean squared diff
        #pragma unroll
        for (int b = 0; b < NBINS; ++b) {
            float s   = cells[b];
            float ss  = cells[16 + b];
            float cnt = cells[32 + b];
            if (cnt > 1.0f)
                loss += (ss - s * s / cnt) / (cnt - 1.0f);  // unbiased var
        }
        out[0] = 0.1f * loss;   // LMBDA
    }
}

extern "C" void kernel_launch(void* const* d_in, const int* in_sizes, int n_in,
                              void* d_out, int out_size, void* d_ws, size_t ws_size,
                              hipStream_t stream)
{
    const float* w     = (const float*)d_in[0];
    const float* wq    = (const float*)d_in[1];
    const int*   nbit  = (const int*)d_in[2];
    const float* alpha = (const float*)d_in[3];
    float* out     = (float*)d_out;
    float* partial = (float*)d_ws;            // 49*GRID floats, fully overwritten
    float* cells   = partial + 49 * GRID;     // 49 floats
    long long n = (long long)in_sizes[0];

    binreg_main  <<<GRID, TPB, 0, stream>>>(w, wq, alpha, nbit, partial, n);
    binreg_final1<<<49,   TPB, 0, stream>>>(partial, cells);
    binreg_final2<<<1,    64,  0, stream>>>(cells, out, n);
}

// Round 6
// 542.784 us; speedup vs baseline: 1.0497x; 1.0497x over previous
//
#include <hip/hip_runtime.h>

#define NBINS 16
#define TPB   256
#define GRID  1280          // 5 blocks/CU x 256 CUs; 5 x 32KB = 160KB LDS exactly

// d_ws layout: partial[c * GRID + blk], c: 0..15 sum, 16..31 sumsq, 32..47 cnt,
// 48 = sum (wq-w)^2.  cells[49] at partial + 49*GRID.
//
// History: LDS atomics (CAS R1: 1026us, ds_add_f32 R3: 1010us) ~6x slower than
// plain RMW (R2/R4 ~165us). Bank conflicts NOT the limiter (R4==R2). Ballot
// counts cost ~64 VALU/iter and regressed (R5: 213us). This round: prefetch
// decouples global loads from the serialized DS RMW chain; counts in a
// nibble-packed uint64 register flushed to 16 int regs every 3 iters.

__global__ __launch_bounds__(TPB, 5) void binreg_main(
    const float* __restrict__ w, const float* __restrict__ wq,
    const float* __restrict__ alpha_p, const int* __restrict__ nbit_p,
    float* __restrict__ partial, long long n)
{
    // {sum, sumsq} per (bin, thread); column layout: addr = bin*256+tid ->
    // bank = tid%32 regardless of data-dependent bin (2-way aliasing = free).
    __shared__ float2 sv[NBINS * TPB];          // 32768 B exactly

    const int tid = threadIdx.x;

    #pragma unroll
    for (int k = 0; k < NBINS; ++k) sv[k * TPB + tid] = make_float2(0.0f, 0.0f);
    // columns are thread-private until the epilogue fold; no barrier needed

    const float inv_a = 1.0f / alpha_p[0];
    const int   qoff  = 1 << (nbit_p[0] - 1);   // -Qn = 8 for nbit=4

    const long long n4     = n >> 2;
    const long long stride = (long long)GRID * TPB;
    const float4* w4 = (const float4*)w;
    const float4* q4 = (const float4*)wq;

    float sq = 0.0f;
    unsigned long long nib = 0ull;   // 16 x 4-bit per-bin counters
    int cnt[NBINS];
    #pragma unroll
    for (int k = 0; k < NBINS; ++k) cnt[k] = 0;
    int fc = 3;                      // flush every 3 iters (<=12 adds < 16 cap)

    long long i = (long long)blockIdx.x * TPB + tid;
    bool valid = i < n4;
    float4 a, b;
    if (valid) { a = w4[i]; b = q4[i]; }

    while (valid) {
        // prefetch next iteration BEFORE the DS chain -> loads stay in flight
        long long ni = i + stride;
        bool nvalid = ni < n4;
        float4 an, bn;
        if (nvalid) { an = w4[ni]; bn = q4[ni]; }

        float d0 = b.x - a.x, d1 = b.y - a.y, d2 = b.z - a.z, d3 = b.w - a.w;
        sq += d0 * d0 + d1 * d1 + d2 * d2 + d3 * d3;

        int b0 = ((int)rintf(b.x * inv_a) + qoff) & (NBINS - 1);
        int b1 = ((int)rintf(b.y * inv_a) + qoff) & (NBINS - 1);
        int b2 = ((int)rintf(b.z * inv_a) + qoff) & (NBINS - 1);
        int b3 = ((int)rintf(b.w * inv_a) + qoff) & (NBINS - 1);

        // counts: 4-bit fields in a register; ~3 VALU/element, zero DS ops
        nib += (1ull << (b0 << 2)) + (1ull << (b1 << 2))
             + (1ull << (b2 << 2)) + (1ull << (b3 << 2));
        if (--fc == 0) {
            #pragma unroll
            for (int k = 0; k < NBINS; ++k)
                cnt[k] += (int)((nib >> (k * 4)) & 0xFull);
            nib = 0ull; fc = 3;
        }

        int i0 = (b0 << 8) + tid;
        int i1 = (b1 << 8) + tid;
        int i2 = (b2 << 8) + tid;
        int i3 = (b3 << 8) + tid;

        // 4 RMW segments; may alias (same-bin components) -> program order,
        // which the in-order DS pipe preserves within a wave.
        { float2 t = sv[i0]; t.x += a.x; t.y += a.x * a.x; sv[i0] = t; }
        { float2 t = sv[i1]; t.x += a.y; t.y += a.y * a.y; sv[i1] = t; }
        { float2 t = sv[i2]; t.x += a.z; t.y += a.z * a.z; sv[i2] = t; }
        { float2 t = sv[i3]; t.x += a.w; t.y += a.w * a.w; sv[i3] = t; }

        i = ni; valid = nvalid; a = an; b = bn;
    }

    // scalar tail (n divisible by 4 in practice; safety only)
    for (long long t4 = (n4 << 2) + (long long)blockIdx.x * TPB + tid; t4 < n; t4 += stride) {
        float av = w[t4], bv = wq[t4];
        float d = bv - av;
        sq += d * d;
        int bb = ((int)rintf(bv * inv_a) + qoff) & (NBINS - 1);
        nib += 1ull << (bb << 2);
        #pragma unroll
        for (int k = 0; k < NBINS; ++k)
            cnt[k] += (int)((nib >> (k * 4)) & 0xFull);
        nib = 0ull;
        int ii = (bb << 8) + tid;
        float2 t = sv[ii]; t.x += av; t.y += av * av; sv[ii] = t;
    }
    // final flush of any residual nibble counts
    #pragma unroll
    for (int k = 0; k < NBINS; ++k)
        cnt[k] += (int)((nib >> (k * 4)) & 0xFull);

    // wave-reduce sq and cnt[]
    for (int off = 32; off; off >>= 1) sq += __shfl_down(sq, off, 64);
    #pragma unroll
    for (int k = 0; k < NBINS; ++k)
        for (int off = 32; off; off >>= 1) cnt[k] += __shfl_down(cnt[k], off, 64);

    const int wave = tid >> 6, lane = tid & 63;
    __syncthreads();   // all sv columns final & visible

    // fold 256 columns -> 32 block partials (s, ss); wave v: cells v, v+4, ...
    for (int c = wave; c < 32; c += 4) {
        const int bin = c & 15;
        float v = 0.0f;
        #pragma unroll
        for (int r = 0; r < TPB / 64; ++r) {
            float2 t = sv[(bin << 8) + r * 64 + lane];
            v += (c < 16) ? t.x : t.y;
        }
        for (int off = 32; off; off >>= 1) v += __shfl_down(v, off, 64);
        if (lane == 0) partial[c * GRID + blockIdx.x] = v;
    }
    __syncthreads();   // fold complete; sv reusable as staging

    float* stage = (float*)sv;   // 68 floats reused
    if (lane == 0) {
        #pragma unroll
        for (int k = 0; k < NBINS; ++k) stage[wave * NBINS + k] = (float)cnt[k];
        stage[64 + wave] = sq;
    }
    __syncthreads();

    if (tid < NBINS) {
        float v = stage[tid] + stage[16 + tid] + stage[32 + tid] + stage[48 + tid];
        partial[(32 + tid) * GRID + blockIdx.x] = v;
    }
    if (tid == 16)
        partial[48 * GRID + blockIdx.x] =
            (stage[64] + stage[65]) + (stage[66] + stage[67]);
}

// stage 1: one block per cell, reduce GRID partials -> cells[c]
__global__ __launch_bounds__(TPB) void binreg_final1(
    const float* __restrict__ partial, float* __restrict__ cells)
{
    const int c = blockIdx.x;
    const int tid = threadIdx.x, wave = tid >> 6, lane = tid & 63;
    __shared__ float wsum[4];

    float v = 0.0f;
    for (int r = tid; r < GRID; r += TPB) v += partial[c * GRID + r];
    for (int off = 32; off; off >>= 1) v += __shfl_down(v, off, 64);
    if (lane == 0) wsum[wave] = v;
    __syncthreads();
    if (tid == 0) cells[c] = (wsum[0] + wsum[1]) + (wsum[2] + wsum[3]);
}

// stage 2: combine 49 cells into the loss scalar
__global__ void binreg_final2(const float* __restrict__ cells,
                              float* __restrict__ out, long long n)
{
    if (threadIdx.x == 0 && blockIdx.x == 0) {
        float loss = cells[48] / (float)n;   // mean squared diff
        #pragma unroll
        for (int b = 0; b < NBINS; ++b) {
            float s   = cells[b];
            float ss  = cells[16 + b];
            float cnt = cells[32 + b];
            if (cnt > 1.0f)
                loss += (ss - s * s / cnt) / (cnt - 1.0f);  // unbiased var
        }
        out[0] = 0.1f * loss;   // LMBDA
    }
}

extern "C" void kernel_launch(void* const* d_in, const int* in_sizes, int n_in,
                              void* d_out, int out_size, void* d_ws, size_t ws_size,
                              hipStream_t stream)
{
    const float* w     = (const float*)d_in[0];
    const float* wq    = (const float*)d_in[1];
    const int*   nbit  = (const int*)d_in[2];
    const float* alpha = (const float*)d_in[3];
    float* out     = (float*)d_out;
    float* partial = (float*)d_ws;            // 49*GRID floats, fully overwritten
    float* cells   = partial + 49 * GRID;     // 49 floats
    long long n = (long long)in_sizes[0];

    binreg_main  <<<GRID, TPB, 0, stream>>>(w, wq, alpha, nbit, partial, n);
    binreg_final1<<<49,   TPB, 0, stream>>>(partial, cells);
    binreg_final2<<<1,    64,  0, stream>>>(cells, out, n);
}